// Round 9
// baseline (554.741 us; speedup 1.0000x reference)
//
#include <hip/hip_runtime.h>
#include <hip/hip_bf16.h>
#include <math.h>

#define S_LEN 4096
#define HIDDEN 2048
#define NH 16
#define QLORA 768
#define KVLORA 512
#define DROPE 64
#define DV 128
#define TOPK 1024
#define DQK 192

typedef __attribute__((ext_vector_type(4))) float f32x4;
typedef __attribute__((ext_vector_type(8))) __bf16 bf16x8;
typedef unsigned short u16;
typedef unsigned int u32;

__device__ __forceinline__ u16 f2bf(float f) {
    union { float f; u32 u; } v; v.f = f;
    u32 r = v.u + 0x7fffu + ((v.u >> 16) & 1u);
    return (u16)(r >> 16);
}

// async global->LDS 16B: per-lane global src, wave-uniform LDS base (+lane*16 implied)
__device__ __forceinline__ void gll16(const u16* g, u16* l) {
    __builtin_amdgcn_global_load_lds((const void*)g, (void*)l, 16, 0, 0);
}

// ---------------- fp32 -> bf16 cast (hidden_states) ----------------
__global__ __launch_bounds__(256) void k_cast(const float* __restrict__ src,
                                              u16* __restrict__ dst, int n4) {
    int i = blockIdx.x * 256 + threadIdx.x;
    if (i >= n4) return;
    float4 v = ((const float4*)src)[i];
    union { u16 h[4]; uint2 u; } o;
    o.h[0] = f2bf(v.x); o.h[1] = f2bf(v.y);
    o.h[2] = f2bf(v.z); o.h[3] = f2bf(v.w);
    ((uint2*)dst)[i] = o.u;
}

// ---------------- YaRN cos/sin table ----------------
__global__ __launch_bounds__(256) void k_yarn(const int* __restrict__ pos_ids,
                                              float* __restrict__ cos_t,
                                              float* __restrict__ sin_t) {
    int idx = blockIdx.x * 256 + threadIdx.x;     // S*32 entries
    if (idx >= S_LEN * 32) return;
    int s = idx >> 5, i = idx & 31;
    float pos = (float)pos_ids[s];
    float inv = expf(-(float)i * 0.503690489092448f) * (1.0f / 1024.0f);
    float ang = pos * inv;
    const float MS2 = 1.8132604f;                 // (0.1*ln(32)+1)^2
    float sv, cv;
    sincosf(ang, &sv, &cv);
    cos_t[idx] = cv * MS2;
    sin_t[idx] = sv * MS2;
}

// ---------------- weight transpose+cast  W[K,N] fp32 -> Wt[N,K] bf16 ----------------
__global__ __launch_bounds__(256) void k_transpose(const float* __restrict__ src,
                                                   u16* __restrict__ dst,
                                                   int K, int N) {
    __shared__ u16 t[32][33];
    int n0 = blockIdx.x * 32, k0 = blockIdx.y * 32;
    int tx = threadIdx.x & 31, ty = threadIdx.x >> 5;   // 32 x 8
    #pragma unroll
    for (int i = 0; i < 32; i += 8)
        t[ty + i][tx] = f2bf(src[(long)(k0 + ty + i) * N + n0 + tx]);
    __syncthreads();
    #pragma unroll
    for (int i = 0; i < 32; i += 8)
        dst[(long)(n0 + ty + i) * K + k0 + tx] = t[tx][ty + i];
}

// ---------------- m97-style bf16 GEMM: C = A[M,K] @ Bt[N,K]^T ----------------
// 128x128 tile, BK=32, global_load_lds staging, linear LDS [128][32].
template <int MODE>
__global__ __launch_bounds__(256) void k_gemm(const u16* __restrict__ A,
                                              const u16* __restrict__ Bt,
                                              void* __restrict__ out0,
                                              void* __restrict__ out1,
                                              const float* __restrict__ cos_t,
                                              const float* __restrict__ sin_t,
                                              int M, int N, int K) {
    __shared__ u16 lA[128 * 32];
    __shared__ u16 lB[128 * 32];
    const int bm = blockIdx.y, bn = blockIdx.x;
    const int tid = threadIdx.x;
    const int lane = tid & 63, wid = tid >> 6;
    const int wr = wid >> 1, wc = wid & 1;
    const int l15 = lane & 15, l4 = lane >> 4;

    f32x4 acc[4][4];
    #pragma unroll
    for (int i = 0; i < 4; ++i)
        #pragma unroll
        for (int j = 0; j < 4; ++j) acc[i][j] = f32x4{0.f, 0.f, 0.f, 0.f};

    const int srow = wid * 32 + (lane >> 2);
    const int scol = (lane & 3) * 8;
    const u16* gA = A + (long)(bm * 128 + srow) * K + scol;
    const u16* gB = Bt + (long)(bn * 128 + srow) * K + scol;
    u16* lA0 = lA + wid * 1024;
    u16* lB0 = lB + wid * 1024;
    const long kstep16 = 16L * K;

    const int nkt = K >> 5;
    for (int kt = 0; kt < nkt; ++kt) {
        const u16* pa = gA + kt * 32;
        const u16* pb = gB + kt * 32;
        gll16(pa, lA0);
        gll16(pa + kstep16, lA0 + 512);
        gll16(pb, lB0);
        gll16(pb + kstep16, lB0 + 512);
        __syncthreads();

        bf16x8 af[4], bfr[4];
        #pragma unroll
        for (int mr = 0; mr < 4; ++mr)
            af[mr] = *(const bf16x8*)(&lA[(wr * 64 + mr * 16 + l15) * 32 + l4 * 8]);
        #pragma unroll
        for (int nc = 0; nc < 4; ++nc)
            bfr[nc] = *(const bf16x8*)(&lB[(wc * 64 + nc * 16 + l15) * 32 + l4 * 8]);
        #pragma unroll
        for (int mr = 0; mr < 4; ++mr)
            #pragma unroll
            for (int nc = 0; nc < 4; ++nc)
                acc[mr][nc] = __builtin_amdgcn_mfma_f32_16x16x32_bf16(
                    af[mr], bfr[nc], acc[mr][nc], 0, 0, 0);
        __syncthreads();
    }

    const int row0 = bm * 128 + wr * 64;
    const int col0 = bn * 128 + wc * 64;
    #pragma unroll
    for (int mr = 0; mr < 4; ++mr) {
        #pragma unroll
        for (int nc = 0; nc < 4; ++nc) {
            #pragma unroll
            for (int jj = 0; jj < 4; ++jj) {
                int row = row0 + mr * 16 + l4 * 4 + jj;
                int col = col0 + nc * 16 + l15;
                float v = acc[mr][nc][jj];
                if (MODE == 0) {
                    if (col < QLORA)
                        ((float*)out0)[(long)row * QLORA + col] = v;
                    else if (col < QLORA + KVLORA + DROPE)
                        ((float*)out1)[(long)row * (KVLORA + DROPE) + (col - QLORA)] = v;
                } else if (MODE == 1) {
                    if (col < NH * DV) {
                        int h = col >> 7, d = col & 127;
                        ((u16*)out0)[((long)h * S_LEN + row) * DQK + d] = f2bf(v);
                    } else {
                        // fused YaRN RoPE: partner j^32 lives at acc[mr][nc^2][jj]
                        int c2 = col - NH * DV;
                        int h = c2 >> 6, j = c2 & 63, i = j & 31;
                        float c = cos_t[row * 32 + i], sn = sin_t[row * 32 + i];
                        float xp = acc[mr][nc ^ 2][jj];
                        float val = (j < 32) ? v * c - xp * sn : v * c + xp * sn;
                        ((u16*)out0)[((long)h * S_LEN + row) * DQK + DV + j] = f2bf(val);
                    }
                } else if (MODE == 2) {
                    int h = col >> 8, rr = col & 255;
                    if (rr < 128)
                        ((u16*)out0)[((long)h * S_LEN + row) * DV + rr] = f2bf(v);
                    else
                        ((u16*)out1)[((long)h * S_LEN + row) * DV + (rr - 128)] = f2bf(v);
                } else {
                    ((float*)out0)[(long)row * N + col] = v;
                }
            }
        }
    }
}

// ---------------- RMSNorm (q path, C=768) ----------------
__global__ __launch_bounds__(256) void k_rms_q(const float* __restrict__ q_lr,
                                               const float* __restrict__ w,
                                               u16* __restrict__ q_latent) {
    int s = blockIdx.x;
    const float* x = q_lr + (long)s * QLORA;
    int t = threadIdx.x;
    float v0 = x[t], v1 = x[t + 256], v2 = x[t + 512];
    float ss = v0 * v0 + v1 * v1 + v2 * v2;
    #pragma unroll
    for (int off = 32; off >= 1; off >>= 1) ss += __shfl_xor(ss, off);
    __shared__ float red[4];
    if ((t & 63) == 0) red[t >> 6] = ss;
    __syncthreads();
    ss = red[0] + red[1] + red[2] + red[3];
    float inv = rsqrtf(ss / (float)QLORA + 1e-6f);
    u16* o = q_latent + (long)s * QLORA;
    o[t]       = f2bf(v0 * inv * w[t]);
    o[t + 256] = f2bf(v1 * inv * w[t + 256]);
    o[t + 512] = f2bf(v2 * inv * w[t + 512]);
}

// ---------------- RMSNorm (kv, C=512) + k_rope rotation ----------------
__global__ __launch_bounds__(256) void k_kv_norm_rope(const float* __restrict__ kv_lr,
                                                      const float* __restrict__ w,
                                                      const float* __restrict__ cos_t,
                                                      const float* __restrict__ sin_t,
                                                      u16* __restrict__ kv_latent,
                                                      u16* __restrict__ krope) {
    int s = blockIdx.x;
    const float* x = kv_lr + (long)s * (KVLORA + DROPE);
    int t = threadIdx.x;
    float v0 = x[t], v1 = x[t + 256];
    float ss = v0 * v0 + v1 * v1;
    #pragma unroll
    for (int off = 32; off >= 1; off >>= 1) ss += __shfl_xor(ss, off);
    __shared__ float red[4];
    if ((t & 63) == 0) red[t >> 6] = ss;
    __syncthreads();
    ss = red[0] + red[1] + red[2] + red[3];
    float inv = rsqrtf(ss / (float)KVLORA + 1e-6f);
    u16* o = kv_latent + (long)s * KVLORA;
    o[t]       = f2bf(v0 * inv * w[t]);
    o[t + 256] = f2bf(v1 * inv * w[t + 256]);
    if (t < DROPE) {
        int i = t & 31;
        float c = cos_t[s * 32 + i], sn = sin_t[s * 32 + i];
        float xr = x[KVLORA + t];
        float xp = x[KVLORA + ((t < 32) ? t + 32 : t - 32)];
        float val = (t < 32) ? xr * c - xp * sn : xr * c + xp * sn;
        krope[(long)s * DROPE + t] = f2bf(val);
    }
}

// ---------------- gather: k_g row-major [h][j][192], v_g_t transposed [h][kt][d][64] ----------------
__global__ void k_gather(const int* __restrict__ idx,
                         const u16* __restrict__ k_buf,
                         const u16* __restrict__ v_buf,
                         const u16* __restrict__ krope,
                         u16* __restrict__ k_g, u16* __restrict__ v_g_t) {
    int j = blockIdx.x, h = blockIdx.y, t = threadIdx.x;  // 64 threads
    int src = idx[j];
    const uint4* kb = (const uint4*)(k_buf + ((long)h * S_LEN + src) * DV);
    const uint4* kr = (const uint4*)(krope + (long)src * DROPE);
    uint4* kgp = (uint4*)(k_g + ((long)h * TOPK + j) * DQK);
    if (t < 16)       kgp[t] = kb[t];
    else if (t < 24)  kgp[t] = kr[t - 16];
    // V transposed: thread t handles d = 2t, 2t+1 for key j
    u32 vv = *(const u32*)(v_buf + ((long)h * S_LEN + src) * DV + t * 2);
    int kt = j >> 6, jin = j & 63;
    u16* base = v_g_t + ((long)(h * 16 + kt) * 128) * 64 + jin;
    base[(2 * t) * 64]     = (u16)(vv & 0xffff);
    base[(2 * t + 1) * 64] = (u16)(vv >> 16);
}

// ---------------- flash attention, barrier-free, K/V direct from L2 ----------------
// grid 512: block = (head, 128 q-rows); 4 waves x 32 q (2 sub-tiles of 16).
// K/V per head = 640KB, 2 heads pinned per XCD -> L2-resident. No __syncthreads:
// only per-wave lP (P transpose for PV A-operand) lives in LDS.
__global__ __launch_bounds__(256) void k_attn(const u16* __restrict__ qf,
                                              const u16* __restrict__ kg,
                                              const u16* __restrict__ vgt,
                                              u16* __restrict__ attn_out) {
    __shared__ u16 lP[4][2][16 * 72];   // [wave][qs][q16 x key64 pad->72] = 18.4KB
    const int b = blockIdx.x;
    const int h = (b & 7) * 2 + ((b >> 3) & 1);   // XCD-pinned heads
    const int qt = b >> 4;                         // 0..31
    const int tid = threadIdx.x, lane = tid & 63, wid = tid >> 6;
    const int l15 = lane & 15, l4 = lane >> 4;

    bf16x8 qfr[2][6];
    #pragma unroll
    for (int qs = 0; qs < 2; ++qs) {
        const u16* qrow = qf + ((long)h * S_LEN + qt * 128 + wid * 32 + qs * 16 + l15) * DQK + l4 * 8;
        #pragma unroll
        for (int kd = 0; kd < 6; ++kd) qfr[qs][kd] = *(const bf16x8*)(qrow + kd * 32);
    }
    float m[2][4], l[2][4];
    #pragma unroll
    for (int qs = 0; qs < 2; ++qs)
        #pragma unroll
        for (int jj = 0; jj < 4; ++jj) { m[qs][jj] = -1e30f; l[qs][jj] = 0.f; }
    f32x4 acc_o[2][8];
    #pragma unroll
    for (int qs = 0; qs < 2; ++qs)
        #pragma unroll
        for (int nc = 0; nc < 8; ++nc) acc_o[qs][nc] = f32x4{0.f, 0.f, 0.f, 0.f};

    const float scale = 0.07216878364870323f;  // 1/sqrt(192)

    for (int kt = 0; kt < TOPK / 64; ++kt) {
        // S = Q @ K^T for both q sub-tiles, K fragments straight from global (L2)
        f32x4 sa[2][4];
        #pragma unroll
        for (int kc = 0; kc < 4; ++kc) {
            const u16* kbase = kg + ((long)h * TOPK + kt * 64 + kc * 16 + l15) * DQK + l4 * 8;
            bf16x8 kf[6];
            #pragma unroll
            for (int kd = 0; kd < 6; ++kd) kf[kd] = *(const bf16x8*)(kbase + kd * 32);
            sa[0][kc] = f32x4{0.f, 0.f, 0.f, 0.f};
            sa[1][kc] = f32x4{0.f, 0.f, 0.f, 0.f};
            #pragma unroll
            for (int kd = 0; kd < 6; ++kd) {
                sa[0][kc] = __builtin_amdgcn_mfma_f32_16x16x32_bf16(qfr[0][kd], kf[kd], sa[0][kc], 0, 0, 0);
                sa[1][kc] = __builtin_amdgcn_mfma_f32_16x16x32_bf16(qfr[1][kd], kf[kd], sa[1][kc], 0, 0, 0);
            }
            sa[0][kc] *= scale;
            sa[1][kc] *= scale;
        }
        // online softmax per qs; P -> per-wave LDS (transpose for PV A-operand)
        #pragma unroll
        for (int qs = 0; qs < 2; ++qs) {
            float fac[4], psum[4];
            #pragma unroll
            for (int jj = 0; jj < 4; ++jj) {
                float mx = fmaxf(fmaxf(sa[qs][0][jj], sa[qs][1][jj]),
                                 fmaxf(sa[qs][2][jj], sa[qs][3][jj]));
                #pragma unroll
                for (int off = 1; off <= 8; off <<= 1) mx = fmaxf(mx, __shfl_xor(mx, off));
                float mnew = fmaxf(m[qs][jj], mx);
                fac[jj] = __expf(m[qs][jj] - mnew);
                m[qs][jj] = mnew;
                psum[jj] = 0.f;
            }
            #pragma unroll
            for (int kc = 0; kc < 4; ++kc) {
                #pragma unroll
                for (int jj = 0; jj < 4; ++jj) {
                    float p = __expf(sa[qs][kc][jj] - m[qs][jj]);
                    psum[jj] += p;
                    lP[wid][qs][(l4 * 4 + jj) * 72 + kc * 16 + l15] = f2bf(p);
                }
            }
            #pragma unroll
            for (int jj = 0; jj < 4; ++jj) {
                #pragma unroll
                for (int off = 1; off <= 8; off <<= 1) psum[jj] += __shfl_xor(psum[jj], off);
                l[qs][jj] = l[qs][jj] * fac[jj] + psum[jj];
            }
            #pragma unroll
            for (int nc = 0; nc < 8; ++nc)
                #pragma unroll
                for (int jj = 0; jj < 4; ++jj) acc_o[qs][nc][jj] *= fac[jj];
        }
        // O += P @ V ; V^T fragments straight from global (L2), shared across qs
        #pragma unroll
        for (int kc2 = 0; kc2 < 2; ++kc2) {
            bf16x8 pf0 = *(const bf16x8*)(&lP[wid][0][l15 * 72 + kc2 * 32 + l4 * 8]);
            bf16x8 pf1 = *(const bf16x8*)(&lP[wid][1][l15 * 72 + kc2 * 32 + l4 * 8]);
            #pragma unroll
            for (int nc = 0; nc < 8; ++nc) {
                const u16* vbase = vgt + ((long)(h * 16 + kt) * 128 + nc * 16 + l15) * 64 + kc2 * 32 + l4 * 8;
                bf16x8 vf = *(const bf16x8*)(vbase);
                acc_o[0][nc] = __builtin_amdgcn_mfma_f32_16x16x32_bf16(pf0, vf, acc_o[0][nc], 0, 0, 0);
                acc_o[1][nc] = __builtin_amdgcn_mfma_f32_16x16x32_bf16(pf1, vf, acc_o[1][nc], 0, 0, 0);
            }
        }
    }
    #pragma unroll
    for (int qs = 0; qs < 2; ++qs) {
        int row = qt * 128 + wid * 32 + qs * 16 + l4 * 4;
        #pragma unroll
        for (int nc = 0; nc < 8; ++nc)
            #pragma unroll
            for (int jj = 0; jj < 4; ++jj) {
                float v = acc_o[qs][nc][jj] / l[qs][jj];
                attn_out[(long)(row + jj) * (NH * DV) + h * DV + nc * 16 + l15] = f2bf(v);
            }
    }
}

// ---------------- launch ----------------
extern "C" void kernel_launch(void* const* d_in, const int* in_sizes, int n_in,
                              void* d_out, int out_size, void* d_ws, size_t ws_size,
                              hipStream_t stream) {
    const float* hs      = (const float*)d_in[0];
    const int*   pos     = (const int*)d_in[1];
    const int*   dsa     = (const int*)d_in[2];
    const float* wq_a    = (const float*)d_in[3];
    const float* q_ln    = (const float*)d_in[4];
    const float* wq_b    = (const float*)d_in[5];
    const float* wq_rope = (const float*)d_in[6];
    const float* wkv_a   = (const float*)d_in[7];
    const float* kv_ln   = (const float*)d_in[8];
    const float* wkv_b   = (const float*)d_in[9];
    const float* wo      = (const float*)d_in[10];
    float* out = (float*)d_out;

    char* ws = (char*)d_ws;
    auto alloc = [&](size_t bytes) {
        char* p = ws; ws += (bytes + 255) & ~(size_t)255; return p;
    };
    u16* W1t  = (u16*)alloc(1408L * 2048 * 2);  // [wq_a_t ; wkv_a_t], padded to 11*128 rows
    u16* W2t  = (u16*)alloc(3072L * 768 * 2);   // [wq_b_t ; wq_rope_t]
    u16* W3t  = (u16*)alloc(4096L * 512 * 2);   // wkv_b_t
    u16* W4t  = (u16*)alloc(2048L * 2048 * 2);  // wo_t
    float* q_lr  = (float*)alloc(4096L * 768 * 4);
    float* kv_lr = (float*)alloc(4096L * 576 * 4);
    u16* q_latent   = (u16*)alloc(4096L * 768 * 2);
    u16* kv_latent  = (u16*)alloc(4096L * 512 * 2);
    u16* q_full     = (u16*)alloc(16L * 4096 * 192 * 2);
    u16* k_buf      = (u16*)alloc(16L * 4096 * 128 * 2);
    u16* v_buf      = (u16*)alloc(16L * 4096 * 128 * 2);
    float* cos_t    = (float*)alloc(4096L * 32 * 4);
    float* sin_t    = (float*)alloc(4096L * 32 * 4);
    // Union: hs_bf16 (16.8MB, dead after G1) overlaps k_g/v_g_t/krope (11MB, written post-G3).
    char* late = alloc(16L * 4096 * 2 * 2);
    u16* hs_bf = (u16*)late;                       // 4096*2048 bf16
    u16* k_g   = (u16*)late;                       // 16*1024*192
    u16* v_g_t = k_g + 16L * 1024 * 192;           // 16*16*128*64
    u16* krope = v_g_t + 16L * 1024 * 128;         // 4096*64
    // attn output aliases q_lr+kv_lr region (both dead by then)
    u16* attn_o = (u16*)q_lr;

    k_yarn<<<dim3(512), dim3(256), 0, stream>>>(pos, cos_t, sin_t);
    k_cast<<<dim3(8192), dim3(256), 0, stream>>>(hs, hs_bf, 4096 * 2048 / 4);

    k_transpose<<<dim3(768 / 32, 2048 / 32), 256, 0, stream>>>(wq_a, W1t, 2048, 768);
    k_transpose<<<dim3(576 / 32, 2048 / 32), 256, 0, stream>>>(wkv_a, W1t + 768L * 2048, 2048, 576);
    k_transpose<<<dim3(2048 / 32, 768 / 32), 256, 0, stream>>>(wq_b, W2t, 768, 2048);
    k_transpose<<<dim3(1024 / 32, 768 / 32), 256, 0, stream>>>(wq_rope, W2t + 2048L * 768, 768, 1024);
    k_transpose<<<dim3(4096 / 32, 512 / 32), 256, 0, stream>>>(wkv_b, W3t, 512, 4096);
    k_transpose<<<dim3(2048 / 32, 2048 / 32), 256, 0, stream>>>(wo, W4t, 2048, 2048);

    // G1: hs @ [wq_a|wkv_a]  (M=4096, N=1344->1408, K=2048) -> q_lr, kv_lr (fp32)
    k_gemm<0><<<dim3(11, 32), 256, 0, stream>>>(hs_bf, W1t, q_lr, kv_lr, nullptr, nullptr, 4096, 1408, 2048);
    k_rms_q<<<4096, 256, 0, stream>>>(q_lr, q_ln, q_latent);
    k_kv_norm_rope<<<4096, 256, 0, stream>>>(kv_lr, kv_ln, cos_t, sin_t, kv_latent, krope);
    // G2: q_latent @ [wq_b|wq_rope]  (N=3072, K=768) -> q_full (RoPE fused)
    k_gemm<1><<<dim3(24, 32), 256, 0, stream>>>(q_latent, W2t, q_full, nullptr, cos_t, sin_t, 4096, 3072, 768);
    // G3: kv_latent @ wkv_b  (N=4096, K=512) -> k_buf, v_buf
    k_gemm<2><<<dim3(32, 32), 256, 0, stream>>>(kv_latent, W3t, k_buf, v_buf, nullptr, nullptr, 4096, 4096, 512);
    k_gather<<<dim3(1024, 16), 64, 0, stream>>>(dsa, k_buf, v_buf, krope, k_g, v_g_t);
    k_attn<<<dim3(512), 256, 0, stream>>>(q_full, k_g, v_g_t, attn_o);
    // G4: attn @ wo  (N=2048, K=2048) -> out (fp32)
    k_gemm<3><<<dim3(16, 32), 256, 0, stream>>>(attn_o, W4t, out, nullptr, nullptr, nullptr, 4096, 2048, 2048);
}

// Round 10
// 493.933 us; speedup vs baseline: 1.1231x; 1.1231x over previous
//
#include <hip/hip_runtime.h>
#include <hip/hip_bf16.h>
#include <math.h>

#define S_LEN 4096
#define HIDDEN 2048
#define NH 16
#define QLORA 768
#define KVLORA 512
#define DROPE 64
#define DV 128
#define TOPK 1024
#define DQK 192

typedef __attribute__((ext_vector_type(4))) float f32x4;
typedef __attribute__((ext_vector_type(8))) __bf16 bf16x8;
typedef unsigned short u16;
typedef unsigned int u32;

__device__ __forceinline__ u16 f2bf(float f) {
    union { float f; u32 u; } v; v.f = f;
    u32 r = v.u + 0x7fffu + ((v.u >> 16) & 1u);
    return (u16)(r >> 16);
}

// async global->LDS 16B: per-lane global src, wave-uniform LDS base (+lane*16 implied)
__device__ __forceinline__ void gll16(const u16* g, u16* l) {
    __builtin_amdgcn_global_load_lds((const void*)g, (void*)l, 16, 0, 0);
}

// ---------------- fp32 -> bf16 cast (hidden_states) ----------------
__global__ __launch_bounds__(256) void k_cast(const float* __restrict__ src,
                                              u16* __restrict__ dst, int n4) {
    int i = blockIdx.x * 256 + threadIdx.x;
    if (i >= n4) return;
    float4 v = ((const float4*)src)[i];
    union { u16 h[4]; uint2 u; } o;
    o.h[0] = f2bf(v.x); o.h[1] = f2bf(v.y);
    o.h[2] = f2bf(v.z); o.h[3] = f2bf(v.w);
    ((uint2*)dst)[i] = o.u;
}

// ---------------- YaRN cos/sin table ----------------
__global__ __launch_bounds__(256) void k_yarn(const int* __restrict__ pos_ids,
                                              float* __restrict__ cos_t,
                                              float* __restrict__ sin_t) {
    int idx = blockIdx.x * 256 + threadIdx.x;     // S*32 entries
    if (idx >= S_LEN * 32) return;
    int s = idx >> 5, i = idx & 31;
    float pos = (float)pos_ids[s];
    float inv = expf(-(float)i * 0.503690489092448f) * (1.0f / 1024.0f);
    float ang = pos * inv;
    const float MS2 = 1.8132604f;                 // (0.1*ln(32)+1)^2
    float sv, cv;
    sincosf(ang, &sv, &cv);
    cos_t[idx] = cv * MS2;
    sin_t[idx] = sv * MS2;
}

// ---------------- weight transpose+cast  W[K,N] fp32 -> Wt[N,K] bf16 ----------------
__global__ __launch_bounds__(256) void k_transpose(const float* __restrict__ src,
                                                   u16* __restrict__ dst,
                                                   int K, int N) {
    __shared__ u16 t[32][33];
    int n0 = blockIdx.x * 32, k0 = blockIdx.y * 32;
    int tx = threadIdx.x & 31, ty = threadIdx.x >> 5;   // 32 x 8
    #pragma unroll
    for (int i = 0; i < 32; i += 8)
        t[ty + i][tx] = f2bf(src[(long)(k0 + ty + i) * N + n0 + tx]);
    __syncthreads();
    #pragma unroll
    for (int i = 0; i < 32; i += 8)
        dst[(long)(n0 + ty + i) * K + k0 + tx] = t[tx][ty + i];
}

// ---------------- m97-style bf16 GEMM: C = A[M,K] @ Bt[N,K]^T ----------------
template <int MODE>
__global__ __launch_bounds__(256) void k_gemm(const u16* __restrict__ A,
                                              const u16* __restrict__ Bt,
                                              void* __restrict__ out0,
                                              void* __restrict__ out1,
                                              const float* __restrict__ cos_t,
                                              const float* __restrict__ sin_t,
                                              int M, int N, int K) {
    __shared__ u16 lA[128 * 32];
    __shared__ u16 lB[128 * 32];
    const int bm = blockIdx.y, bn = blockIdx.x;
    const int tid = threadIdx.x;
    const int lane = tid & 63, wid = tid >> 6;
    const int wr = wid >> 1, wc = wid & 1;
    const int l15 = lane & 15, l4 = lane >> 4;

    f32x4 acc[4][4];
    #pragma unroll
    for (int i = 0; i < 4; ++i)
        #pragma unroll
        for (int j = 0; j < 4; ++j) acc[i][j] = f32x4{0.f, 0.f, 0.f, 0.f};

    const int srow = wid * 32 + (lane >> 2);
    const int scol = (lane & 3) * 8;
    const u16* gA = A + (long)(bm * 128 + srow) * K + scol;
    const u16* gB = Bt + (long)(bn * 128 + srow) * K + scol;
    u16* lA0 = lA + wid * 1024;
    u16* lB0 = lB + wid * 1024;
    const long kstep16 = 16L * K;

    const int nkt = K >> 5;
    for (int kt = 0; kt < nkt; ++kt) {
        const u16* pa = gA + kt * 32;
        const u16* pb = gB + kt * 32;
        gll16(pa, lA0);
        gll16(pa + kstep16, lA0 + 512);
        gll16(pb, lB0);
        gll16(pb + kstep16, lB0 + 512);
        __syncthreads();

        bf16x8 af[4], bfr[4];
        #pragma unroll
        for (int mr = 0; mr < 4; ++mr)
            af[mr] = *(const bf16x8*)(&lA[(wr * 64 + mr * 16 + l15) * 32 + l4 * 8]);
        #pragma unroll
        for (int nc = 0; nc < 4; ++nc)
            bfr[nc] = *(const bf16x8*)(&lB[(wc * 64 + nc * 16 + l15) * 32 + l4 * 8]);
        #pragma unroll
        for (int mr = 0; mr < 4; ++mr)
            #pragma unroll
            for (int nc = 0; nc < 4; ++nc)
                acc[mr][nc] = __builtin_amdgcn_mfma_f32_16x16x32_bf16(
                    af[mr], bfr[nc], acc[mr][nc], 0, 0, 0);
        __syncthreads();
    }

    const int row0 = bm * 128 + wr * 64;
    const int col0 = bn * 128 + wc * 64;
    #pragma unroll
    for (int mr = 0; mr < 4; ++mr) {
        #pragma unroll
        for (int nc = 0; nc < 4; ++nc) {
            #pragma unroll
            for (int jj = 0; jj < 4; ++jj) {
                int row = row0 + mr * 16 + l4 * 4 + jj;
                int col = col0 + nc * 16 + l15;
                float v = acc[mr][nc][jj];
                if (MODE == 0) {
                    if (col < QLORA)
                        ((float*)out0)[(long)row * QLORA + col] = v;
                    else if (col < QLORA + KVLORA + DROPE)
                        ((float*)out1)[(long)row * (KVLORA + DROPE) + (col - QLORA)] = v;
                } else if (MODE == 1) {
                    if (col < NH * DV) {
                        int h = col >> 7, d = col & 127;
                        ((u16*)out0)[((long)h * S_LEN + row) * DQK + d] = f2bf(v);
                    } else {
                        // fused YaRN RoPE: partner j^32 lives at acc[mr][nc^2][jj]
                        int c2 = col - NH * DV;
                        int h = c2 >> 6, j = c2 & 63, i = j & 31;
                        float c = cos_t[row * 32 + i], sn = sin_t[row * 32 + i];
                        float xp = acc[mr][nc ^ 2][jj];
                        float val = (j < 32) ? v * c - xp * sn : v * c + xp * sn;
                        ((u16*)out0)[((long)h * S_LEN + row) * DQK + DV + j] = f2bf(val);
                    }
                } else if (MODE == 2) {
                    int h = col >> 8, rr = col & 255;
                    if (rr < 128)
                        ((u16*)out0)[((long)h * S_LEN + row) * DV + rr] = f2bf(v);
                    else
                        ((u16*)out1)[((long)h * S_LEN + row) * DV + (rr - 128)] = f2bf(v);
                } else {
                    ((float*)out0)[(long)row * N + col] = v;
                }
            }
        }
    }
}

// ---------------- RMSNorm (q path, C=768) ----------------
__global__ __launch_bounds__(256) void k_rms_q(const float* __restrict__ q_lr,
                                               const float* __restrict__ w,
                                               u16* __restrict__ q_latent) {
    int s = blockIdx.x;
    const float* x = q_lr + (long)s * QLORA;
    int t = threadIdx.x;
    float v0 = x[t], v1 = x[t + 256], v2 = x[t + 512];
    float ss = v0 * v0 + v1 * v1 + v2 * v2;
    #pragma unroll
    for (int off = 32; off >= 1; off >>= 1) ss += __shfl_xor(ss, off);
    __shared__ float red[4];
    if ((t & 63) == 0) red[t >> 6] = ss;
    __syncthreads();
    ss = red[0] + red[1] + red[2] + red[3];
    float inv = rsqrtf(ss / (float)QLORA + 1e-6f);
    u16* o = q_latent + (long)s * QLORA;
    o[t]       = f2bf(v0 * inv * w[t]);
    o[t + 256] = f2bf(v1 * inv * w[t + 256]);
    o[t + 512] = f2bf(v2 * inv * w[t + 512]);
}

// ---------------- RMSNorm (kv, C=512) + k_rope rotation ----------------
__global__ __launch_bounds__(256) void k_kv_norm_rope(const float* __restrict__ kv_lr,
                                                      const float* __restrict__ w,
                                                      const float* __restrict__ cos_t,
                                                      const float* __restrict__ sin_t,
                                                      u16* __restrict__ kv_latent,
                                                      u16* __restrict__ krope) {
    int s = blockIdx.x;
    const float* x = kv_lr + (long)s * (KVLORA + DROPE);
    int t = threadIdx.x;
    float v0 = x[t], v1 = x[t + 256];
    float ss = v0 * v0 + v1 * v1;
    #pragma unroll
    for (int off = 32; off >= 1; off >>= 1) ss += __shfl_xor(ss, off);
    __shared__ float red[4];
    if ((t & 63) == 0) red[t >> 6] = ss;
    __syncthreads();
    ss = red[0] + red[1] + red[2] + red[3];
    float inv = rsqrtf(ss / (float)KVLORA + 1e-6f);
    u16* o = kv_latent + (long)s * KVLORA;
    o[t]       = f2bf(v0 * inv * w[t]);
    o[t + 256] = f2bf(v1 * inv * w[t + 256]);
    if (t < DROPE) {
        int i = t & 31;
        float c = cos_t[s * 32 + i], sn = sin_t[s * 32 + i];
        float xr = x[KVLORA + t];
        float xp = x[KVLORA + ((t < 32) ? t + 32 : t - 32)];
        float val = (t < 32) ? xr * c - xp * sn : xr * c + xp * sn;
        krope[(long)s * DROPE + t] = f2bf(val);
    }
}

// ---------------- gather ----------------
// kgs: K rows pre-swizzled for LDS: per (h,kt) tile of 64 rows x 24 16B-units;
//      unit u of row jin stored at unit (u ^ (jin&7))   [rule-21: swizzle in global,
//      linear global_load_lds, XOR re-applied at ds_read]
// vg:  V transposed [h][kt][d=128][key=64]
__global__ void k_gather(const int* __restrict__ idx,
                         const u16* __restrict__ k_buf,
                         const u16* __restrict__ v_buf,
                         const u16* __restrict__ krope,
                         u16* __restrict__ kgs, u16* __restrict__ vg) {
    int j = blockIdx.x, h = blockIdx.y, t = threadIdx.x;  // 64 threads
    int src = idx[j];
    int kt = j >> 6, jin = j & 63;
    if (t < 24) {
        uint4 val;
        if (t < 16) val = ((const uint4*)(k_buf + ((long)h * S_LEN + src) * DV))[t];
        else        val = ((const uint4*)(krope + (long)src * DROPE))[t - 16];
        int su = t ^ (jin & 7);    // stays within 0..23 (low-3-bit XOR)
        ((uint4*)(kgs + (long)(h * 16 + kt) * 12288 + jin * 192))[su] = val;
    }
    // V transposed: thread t handles d = 2t, 2t+1 for key jin
    u32 vv = *(const u32*)(v_buf + ((long)h * S_LEN + src) * DV + t * 2);
    u16* base = vg + ((long)(h * 16 + kt) * 128) * 64 + jin;
    base[(2 * t) * 64]     = (u16)(vv & 0xffff);
    base[(2 * t + 1) * 64] = (u16)(vv >> 16);
}

// ---------------- flash attention ----------------
// grid 1024: block = (head, 64 q-rows); 4 waves x 16 q each. 33.8KB LDS + <=128 VGPR
// -> 4 blocks/CU. K staged via global_load_lds (pre-swizzled global, linear copy);
// V direct from L2 (2 heads pinned/XCD). Next-tile stage issued before PV (overlap).
__global__ __launch_bounds__(256, 4) void k_attn(const u16* __restrict__ qf,
                                                 const u16* __restrict__ kgs,
                                                 const u16* __restrict__ vg,
                                                 u16* __restrict__ attn_out) {
    __shared__ u16 lK[64 * 192];        // 24KB, swizzled-unit layout
    __shared__ u16 lP[4][16 * 72];      // per-wave P, pad->72 (9.2KB)
    const int b = blockIdx.x;
    const int h = (b & 7) * 2 + ((b >> 3) & 1);   // 2 heads per XCD
    const int qt = b >> 4;                         // 0..63
    const int tid = threadIdx.x, lane = tid & 63, wid = tid >> 6;
    const int l15 = lane & 15, l4 = lane >> 4;

    bf16x8 qfr[6];
    {
        const u16* qrow = qf + ((long)h * S_LEN + qt * 64 + wid * 16 + l15) * DQK + l4 * 8;
        #pragma unroll
        for (int kd = 0; kd < 6; ++kd) qfr[kd] = *(const bf16x8*)(qrow + kd * 32);
    }
    float m[4] = {-1e30f, -1e30f, -1e30f, -1e30f};
    float l[4] = {0.f, 0.f, 0.f, 0.f};
    f32x4 acc[8];
    #pragma unroll
    for (int nc = 0; nc < 8; ++nc) acc[nc] = f32x4{0.f, 0.f, 0.f, 0.f};

    const float scale = 0.07216878364870323f;  // 1/sqrt(192)
    const u16* ktile = kgs + (long)h * 16 * 12288;
    u16* lPw = lP[wid];

    {   // prologue: stage tile 0 (linear copy of pre-swizzled tile)
        const u16* src = ktile + wid * 512 + lane * 8;
        u16* dst = lK + wid * 512;
        #pragma unroll
        for (int i = 0; i < 6; ++i) gll16(src + i * 2048, dst + i * 2048);
    }

    for (int kt = 0; kt < TOPK / 64; ++kt) {
        __syncthreads();    // stage done (compiler drains vmcnt before barrier)
        // S = Q @ K^T  (16q x 64k per wave); kf ds_read re-applies the XOR swizzle
        f32x4 sa[4];
        __builtin_amdgcn_s_setprio(1);
        #pragma unroll
        for (int kc = 0; kc < 4; ++kc) {
            sa[kc] = f32x4{0.f, 0.f, 0.f, 0.f};
            int r = kc * 16 + l15;
            #pragma unroll
            for (int kd = 0; kd < 6; ++kd) {
                int cu = kd * 4 + l4;
                bf16x8 kf = *(const bf16x8*)(&lK[r * 192 + ((cu ^ (r & 7)) * 8)]);
                sa[kc] = __builtin_amdgcn_mfma_f32_16x16x32_bf16(qfr[kd], kf, sa[kc], 0, 0, 0);
            }
            sa[kc] *= scale;
        }
        __builtin_amdgcn_s_setprio(0);
        // online softmax (rows q = l4*4+jj, keys over kc,l15)
        float fac[4], psum[4];
        #pragma unroll
        for (int jj = 0; jj < 4; ++jj) {
            float mx = fmaxf(fmaxf(sa[0][jj], sa[1][jj]), fmaxf(sa[2][jj], sa[3][jj]));
            #pragma unroll
            for (int off = 1; off <= 8; off <<= 1) mx = fmaxf(mx, __shfl_xor(mx, off));
            float mnew = fmaxf(m[jj], mx);
            fac[jj] = __expf(m[jj] - mnew);
            m[jj] = mnew;
            psum[jj] = 0.f;
        }
        #pragma unroll
        for (int kc = 0; kc < 4; ++kc) {
            #pragma unroll
            for (int jj = 0; jj < 4; ++jj) {
                float p = __expf(sa[kc][jj] - m[jj]);
                psum[jj] += p;
                lPw[(l4 * 4 + jj) * 72 + kc * 16 + l15] = f2bf(p);
            }
        }
        #pragma unroll
        for (int jj = 0; jj < 4; ++jj) {
            #pragma unroll
            for (int off = 1; off <= 8; off <<= 1) psum[jj] += __shfl_xor(psum[jj], off);
            l[jj] = l[jj] * fac[jj] + psum[jj];
        }
        #pragma unroll
        for (int nc = 0; nc < 8; ++nc)
            #pragma unroll
            for (int jj = 0; jj < 4; ++jj) acc[nc][jj] *= fac[jj];

        __syncthreads();    // all waves done reading lK
        if (kt < TOPK / 64 - 1) {   // issue next-tile stage BEFORE PV: latency hides under MFMA
            const u16* src = ktile + (kt + 1) * 12288 + wid * 512 + lane * 8;
            u16* dst = lK + wid * 512;
            #pragma unroll
            for (int i = 0; i < 6; ++i) gll16(src + i * 2048, dst + i * 2048);
        }
        // O += P @ V  (V^T direct from global/L2)
        __builtin_amdgcn_s_setprio(1);
        #pragma unroll
        for (int kc2 = 0; kc2 < 2; ++kc2) {
            bf16x8 pf = *(const bf16x8*)(&lPw[l15 * 72 + kc2 * 32 + l4 * 8]);
            #pragma unroll
            for (int nc = 0; nc < 8; ++nc) {
                const u16* vbase = vg + ((long)(h * 16 + kt) * 128 + nc * 16 + l15) * 64 + kc2 * 32 + l4 * 8;
                bf16x8 vf = *(const bf16x8*)(vbase);
                acc[nc] = __builtin_amdgcn_mfma_f32_16x16x32_bf16(pf, vf, acc[nc], 0, 0, 0);
            }
        }
        __builtin_amdgcn_s_setprio(0);
    }
    int row = qt * 64 + wid * 16 + l4 * 4;
    #pragma unroll
    for (int nc = 0; nc < 8; ++nc)
        #pragma unroll
        for (int jj = 0; jj < 4; ++jj) {
            float v = acc[nc][jj] / l[jj];
            attn_out[(long)(row + jj) * (NH * DV) + h * DV + nc * 16 + l15] = f2bf(v);
        }
}

// ---------------- launch ----------------
extern "C" void kernel_launch(void* const* d_in, const int* in_sizes, int n_in,
                              void* d_out, int out_size, void* d_ws, size_t ws_size,
                              hipStream_t stream) {
    const float* hs      = (const float*)d_in[0];
    const int*   pos     = (const int*)d_in[1];
    const int*   dsa     = (const int*)d_in[2];
    const float* wq_a    = (const float*)d_in[3];
    const float* q_ln    = (const float*)d_in[4];
    const float* wq_b    = (const float*)d_in[5];
    const float* wq_rope = (const float*)d_in[6];
    const float* wkv_a   = (const float*)d_in[7];
    const float* kv_ln   = (const float*)d_in[8];
    const float* wkv_b   = (const float*)d_in[9];
    const float* wo      = (const float*)d_in[10];
    float* out = (float*)d_out;

    char* ws = (char*)d_ws;
    auto alloc = [&](size_t bytes) {
        char* p = ws; ws += (bytes + 255) & ~(size_t)255; return p;
    };
    u16* W1t  = (u16*)alloc(1408L * 2048 * 2);  // [wq_a_t ; wkv_a_t], padded to 11*128 rows
    u16* W2t  = (u16*)alloc(3072L * 768 * 2);   // [wq_b_t ; wq_rope_t]
    u16* W3t  = (u16*)alloc(4096L * 512 * 2);   // wkv_b_t
    u16* W4t  = (u16*)alloc(2048L * 2048 * 2);  // wo_t
    float* q_lr  = (float*)alloc(4096L * 768 * 4);
    float* kv_lr = (float*)alloc(4096L * 576 * 4);
    u16* q_latent   = (u16*)alloc(4096L * 768 * 2);
    u16* kv_latent  = (u16*)alloc(4096L * 512 * 2);
    u16* q_full     = (u16*)alloc(16L * 4096 * 192 * 2);
    u16* k_buf      = (u16*)alloc(16L * 4096 * 128 * 2);
    u16* v_buf      = (u16*)alloc(16L * 4096 * 128 * 2);
    float* cos_t    = (float*)alloc(4096L * 32 * 4);
    float* sin_t    = (float*)alloc(4096L * 32 * 4);
    // Union: hs_bf16 (16.8MB, dead after G1) overlaps kgs/vg/krope (11MB, written post-G3).
    char* late = alloc(16L * 4096 * 2 * 2);
    u16* hs_bf = (u16*)late;                       // 4096*2048 bf16
    u16* kgs   = (u16*)late;                       // 16h*16kt*12288 u16 (6.3MB)
    u16* vg    = kgs + 16L * 16 * 12288;           // 16h*16kt*128*64 (4MB)
    u16* krope = vg + 16L * 1024 * 128;            // 4096*64
    // attn output aliases q_lr+kv_lr region (both dead by then)
    u16* attn_o = (u16*)q_lr;

    k_yarn<<<dim3(512), dim3(256), 0, stream>>>(pos, cos_t, sin_t);
    k_cast<<<dim3(8192), dim3(256), 0, stream>>>(hs, hs_bf, 4096 * 2048 / 4);

    k_transpose<<<dim3(768 / 32, 2048 / 32), 256, 0, stream>>>(wq_a, W1t, 2048, 768);
    k_transpose<<<dim3(576 / 32, 2048 / 32), 256, 0, stream>>>(wkv_a, W1t + 768L * 2048, 2048, 576);
    k_transpose<<<dim3(2048 / 32, 768 / 32), 256, 0, stream>>>(wq_b, W2t, 768, 2048);
    k_transpose<<<dim3(1024 / 32, 768 / 32), 256, 0, stream>>>(wq_rope, W2t + 2048L * 768, 768, 1024);
    k_transpose<<<dim3(4096 / 32, 512 / 32), 256, 0, stream>>>(wkv_b, W3t, 512, 4096);
    k_transpose<<<dim3(2048 / 32, 2048 / 32), 256, 0, stream>>>(wo, W4t, 2048, 2048);

    // G1: hs @ [wq_a|wkv_a]  (M=4096, N=1344->1408, K=2048) -> q_lr, kv_lr (fp32)
    k_gemm<0><<<dim3(11, 32), 256, 0, stream>>>(hs_bf, W1t, q_lr, kv_lr, nullptr, nullptr, 4096, 1408, 2048);
    k_rms_q<<<4096, 256, 0, stream>>>(q_lr, q_ln, q_latent);
    k_kv_norm_rope<<<4096, 256, 0, stream>>>(kv_lr, kv_ln, cos_t, sin_t, kv_latent, krope);
    // G2: q_latent @ [wq_b|wq_rope]  (N=3072, K=768) -> q_full (RoPE fused)
    k_gemm<1><<<dim3(24, 32), 256, 0, stream>>>(q_latent, W2t, q_full, nullptr, cos_t, sin_t, 4096, 3072, 768);
    // G3: kv_latent @ wkv_b  (N=4096, K=512) -> k_buf, v_buf
    k_gemm<2><<<dim3(32, 32), 256, 0, stream>>>(kv_latent, W3t, k_buf, v_buf, nullptr, nullptr, 4096, 4096, 512);
    k_gather<<<dim3(1024, 16), 64, 0, stream>>>(dsa, k_buf, v_buf, krope, kgs, vg);
    k_attn<<<dim3(1024), 256, 0, stream>>>(q_full, kgs, vg, attn_o);
    // G4: attn @ wo  (N=2048, K=2048) -> out (fp32)
    k_gemm<3><<<dim3(16, 32), 256, 0, stream>>>(attn_o, W4t, out, nullptr, nullptr, nullptr, 4096, 2048, 2048);
}